// Round 6
// baseline (46.491 us; speedup 1.0000x reference)
//
#include <hip/hip_runtime.h>

typedef __attribute__((ext_vector_type(4))) float f32x4;
typedef __attribute__((ext_vector_type(8))) short bf16x8;

// x: [B, 64, 128] fp32 ; out: [B, 2016] fp32
constexpr int F = 64;
constexpr int D = 128;
constexpr int NPAIR = 2016;   // 64*63/2

// fp32 -> bf16 round-to-nearest-even
__device__ inline unsigned f2bf(float f) {
  unsigned u = __float_as_uint(f);
  return (u + 0x7FFFu + ((u >> 16) & 1u)) >> 16;
}

// One block per batch: 256 threads = 4 waves.
// 10 upper-triangular 16x16 tiles (gram symmetric), 3/3/2/2 across waves.
// All global traffic is touch-once -> non-temporal (no L2/MALL allocate).
__global__ __launch_bounds__(256)
void gram_upper_kernel(const float* __restrict__ x, float* __restrict__ out) {
  // 64 rows x 256 B (bf16), 16B-granule XOR swizzle: granule' = g ^ (row&15)
  // -> conflict-free ds_write_b64 staging AND conflict-free ds_read_b128 frags.
  __shared__ __align__(16) unsigned char lds[F * 256];

  const int b = blockIdx.x;
  const int t = threadIdx.x;
  const float* xb = x + (size_t)b * (F * D);

  // ---- Stage: global fp32 (coalesced float4, nt) -> bf16 -> swizzled LDS ----
#pragma unroll
  for (int k = 0; k < 8; ++k) {
    int idx4 = t + 256 * k;                         // float4 index, [0, 2048)
    f32x4 v = __builtin_nontemporal_load(reinterpret_cast<const f32x4*>(xb) + idx4);
    int e  = idx4 << 2;                             // element index
    int f  = e >> 7;                                // row 0..63
    int d0 = e & 127;                               // col (multiple of 4)
    int off = f * 256 + (((d0 >> 3) ^ (f & 15)) << 4) + ((d0 & 4) << 1);
    uint2 pk;
    pk.x = f2bf(v.x) | (f2bf(v.y) << 16);
    pk.y = f2bf(v.z) | (f2bf(v.w) << 16);
    *reinterpret_cast<uint2*>(lds + off) = pk;
  }
  __syncthreads();

  const int w  = t >> 6;     // wave id
  const int l  = t & 63;
  const int lr = l & 15;     // row-within-tile (A) / col-within-tile (B,D)
  const int lk = l >> 4;     // k-group 0..3

  // Tile schedule: desc byte s = (ti<<4)|tj ; byte 3 = tile count.
  // w0: (0,0)(0,1)(0,2)  w1: (0,3)(1,1)(1,2)  w2: (1,3)(2,2)  w3: (2,3)(3,3)
  const unsigned desc = (w == 0) ? 0x03020100u : (w == 1) ? 0x03121103u
                      : (w == 2) ? 0x02002213u : 0x02003323u;
  const int cnt = desc >> 24;

  float* ob = out + (size_t)b * NPAIR;

#pragma unroll
  for (int s = 0; s < 3; ++s) {
    if (s < cnt) {
      int ti = (desc >> (8 * s + 4)) & 15;
      int tj = (desc >> (8 * s)) & 15;
      f32x4 acc = {0.f, 0.f, 0.f, 0.f};
#pragma unroll
      for (int kk = 0; kk < 4; ++kk) {
        int gsw = ((kk << 2) + lk) ^ lr;   // rows differ by mult of 16 -> same swizzle
        bf16x8 a  = *reinterpret_cast<const bf16x8*>(lds + (ti * 16 + lr) * 256 + gsw * 16);
        bf16x8 bv = *reinterpret_cast<const bf16x8*>(lds + (tj * 16 + lr) * 256 + gsw * 16);
        acc = __builtin_amdgcn_mfma_f32_16x16x32_bf16(a, bv, acc, 0, 0, 0);
      }
      // C/D map: col = lane&15, row = (lane>>4)*4 + reg
      int j  = tj * 16 + lr;
      int ib = ti * 16 + lk * 4;
      if (ti != tj) {
        // off-diagonal tile: every (i,j) has j > i — no predication
#pragma unroll
        for (int r = 0; r < 4; ++r) {
          int i = ib + r;
          int p = i * 63 - ((i * (i - 1)) >> 1) + (j - i - 1);
          __builtin_nontemporal_store(acc[r], ob + p);
        }
      } else {
#pragma unroll
        for (int r = 0; r < 4; ++r) {
          int i = ib + r;
          if (j > i) {
            int p = i * 63 - ((i * (i - 1)) >> 1) + (j - i - 1);
            __builtin_nontemporal_store(acc[r], ob + p);
          }
        }
      }
    }
  }
}

extern "C" void kernel_launch(void* const* d_in, const int* in_sizes, int n_in,
                              void* d_out, int out_size, void* d_ws, size_t ws_size,
                              hipStream_t stream) {
  const float* x = (const float*)d_in[0];
  float* out = (float*)d_out;
  const int B = in_sizes[0] / (F * D);   // 4096
  gram_upper_kernel<<<dim3(B), dim3(256), 0, stream>>>(x, out);
}

// Round 7
// 30.170 us; speedup vs baseline: 1.5410x; 1.5410x over previous
//
#include <hip/hip_runtime.h>

typedef __attribute__((ext_vector_type(4))) float f32x4;
typedef __attribute__((ext_vector_type(8))) short bf16x8;

// x: [B, 64, 128] fp32 ; out: [B, 2016] fp32
constexpr int F = 64;
constexpr int D = 128;
constexpr int NPAIR = 2016;   // 64*63/2

// fp32 -> bf16 round-to-nearest-even
__device__ inline unsigned f2bf(float f) {
  unsigned u = __float_as_uint(f);
  return (u + 0x7FFFu + ((u >> 16) & 1u)) >> 16;
}

// One block per batch: 256 threads = 4 waves.
// 10 upper-triangular 16x16 tiles (gram symmetric), 3/3/2/2 across waves.
// NOTE: plain (cached) stores — nt/write-through regressed 54% (round 6).
__global__ __launch_bounds__(256)
void gram_upper_kernel(const float* __restrict__ x, float* __restrict__ out) {
  // 64 rows x 256 B (bf16), 16B-granule XOR swizzle: granule' = g ^ (row&15)
  // -> conflict-free ds_write_b64 staging AND conflict-free ds_read_b128 frags.
  __shared__ __align__(16) unsigned char lds[F * 256];

  const int b = blockIdx.x;
  const int t = threadIdx.x;
  const float* xb = x + (size_t)b * (F * D);

  // ---- Stage: global fp32 (coalesced float4) -> bf16 -> swizzled LDS ----
#pragma unroll
  for (int k = 0; k < 8; ++k) {
    int idx4 = t + 256 * k;                         // float4 index, [0, 2048)
    f32x4 v = reinterpret_cast<const f32x4*>(xb)[idx4];
    int e  = idx4 << 2;                             // element index
    int f  = e >> 7;                                // row 0..63
    int d0 = e & 127;                               // col (multiple of 4)
    int off = f * 256 + (((d0 >> 3) ^ (f & 15)) << 4) + ((d0 & 4) << 1);
    uint2 pk;
    pk.x = f2bf(v.x) | (f2bf(v.y) << 16);
    pk.y = f2bf(v.z) | (f2bf(v.w) << 16);
    *reinterpret_cast<uint2*>(lds + off) = pk;
  }
  __syncthreads();

  const int w  = t >> 6;     // wave id
  const int l  = t & 63;
  const int lr = l & 15;     // row-within-tile (A) / col-within-tile (B,D)
  const int lk = l >> 4;     // k-group 0..3

  // Tile schedule: desc byte s = (ti<<4)|tj ; byte 3 = tile count.
  // w0: (0,0)(0,1)(0,2)  w1: (0,3)(1,1)(1,2)  w2: (1,3)(2,2)  w3: (2,3)(3,3)
  const unsigned desc = (w == 0) ? 0x03020100u : (w == 1) ? 0x03121103u
                      : (w == 2) ? 0x02002213u : 0x02003323u;
  const int cnt = desc >> 24;

  float* ob = out + (size_t)b * NPAIR;

#pragma unroll
  for (int s = 0; s < 3; ++s) {
    if (s < cnt) {
      int ti = (desc >> (8 * s + 4)) & 15;
      int tj = (desc >> (8 * s)) & 15;
      f32x4 acc = {0.f, 0.f, 0.f, 0.f};
#pragma unroll
      for (int kk = 0; kk < 4; ++kk) {
        int gsw = ((kk << 2) + lk) ^ lr;   // rows differ by mult of 16 -> same swizzle
        bf16x8 a  = *reinterpret_cast<const bf16x8*>(lds + (ti * 16 + lr) * 256 + gsw * 16);
        bf16x8 bv = *reinterpret_cast<const bf16x8*>(lds + (tj * 16 + lr) * 256 + gsw * 16);
        acc = __builtin_amdgcn_mfma_f32_16x16x32_bf16(a, bv, acc, 0, 0, 0);
      }
      // C/D map: col = lane&15, row = (lane>>4)*4 + reg
      int j  = tj * 16 + lr;
      int ib = ti * 16 + lk * 4;
      if (ti != tj) {
        // off-diagonal tile: every (i,j) has j > i — no predication
#pragma unroll
        for (int r = 0; r < 4; ++r) {
          int i = ib + r;
          int p = i * 63 - ((i * (i - 1)) >> 1) + (j - i - 1);
          ob[p] = acc[r];
        }
      } else {
#pragma unroll
        for (int r = 0; r < 4; ++r) {
          int i = ib + r;
          if (j > i) {
            int p = i * 63 - ((i * (i - 1)) >> 1) + (j - i - 1);
            ob[p] = acc[r];
          }
        }
      }
    }
  }
}

extern "C" void kernel_launch(void* const* d_in, const int* in_sizes, int n_in,
                              void* d_out, int out_size, void* d_ws, size_t ws_size,
                              hipStream_t stream) {
  const float* x = (const float*)d_in[0];
  float* out = (float*)d_out;
  const int B = in_sizes[0] / (F * D);   // 4096
  gram_upper_kernel<<<dim3(B), dim3(256), 0, stream>>>(x, out);
}